// Round 11
// baseline (149.391 us; speedup 1.0000x reference)
//
#include <hip/hip_runtime.h>
#include <hip/hip_bf16.h>

typedef __attribute__((ext_vector_type(8))) short short8;     // 8 bf16 (4 VGPRs) MFMA A/B frag
typedef __attribute__((ext_vector_type(4))) float f32x4;      // 16x16 MFMA C/D frag
typedef __attribute__((ext_vector_type(16))) float f32x16;    // 32x32 MFMA C/D frag
typedef __attribute__((ext_vector_type(4))) unsigned short u16x4;
typedef __attribute__((ext_vector_type(4))) unsigned int u32x4;

#define MFMA16(a, b, c) __builtin_amdgcn_mfma_f32_16x16x32_bf16((a), (b), (c), 0, 0, 0)
#define MFMA32(a, b, c) __builtin_amdgcn_mfma_f32_32x32x16_bf16((a), (b), (c), 0, 0, 0)

__device__ __forceinline__ unsigned short f2bf(float f) {
    union { float f; unsigned u; } v; v.f = f;
    return (unsigned short)((v.u + 0x7fffu + ((v.u >> 16) & 1u)) >> 16);
}

__device__ __forceinline__ unsigned cvtpk(float lo, float hi_) {
    unsigned r;
    asm volatile("v_cvt_pk_bf16_f32 %0, %1, %2" : "=v"(r) : "v"(lo), "v"(hi_));
    return r;
}

// ---------------------------------------------------------------- cast X -> bf16
__global__ void cast_x_kernel(const float* __restrict__ x, ushort* __restrict__ y) {
    int i = blockIdx.x * blockDim.x + threadIdx.x;      // one float4 per thread, exact grid
    float4 v = ((const float4*)x)[i];
    u16x4 o = { f2bf(v.x), f2bf(v.y), f2bf(v.z), f2bf(v.w) };
    *(u16x4*)(y + (size_t)i * 4) = o;
}

// ------------------------------------------- W [K][N] f32 -> WT [N][K] bf16
__global__ void transpose_cast_kernel(const float* __restrict__ W, ushort* __restrict__ WT,
                                      int K, int N) {
    __shared__ ushort t[64][66];                        // 66: odd word stride, conflict-free
    int n0 = blockIdx.x * 64, k0 = blockIdx.y * 64;
    int tn = threadIdx.x & 63, tg = threadIdx.x >> 6;
#pragma unroll
    for (int i = 0; i < 16; ++i) {
        int k = tg * 16 + i;
        t[tn][k] = f2bf(W[(size_t)(k0 + k) * N + n0 + tn]);
    }
    __syncthreads();
#pragma unroll
    for (int i = 0; i < 16; ++i) {
        int nn = tg * 16 + i;
        WT[(size_t)(n0 + nn) * K + k0 + tn] = t[nn][tn];
    }
}

// ---------------------------------------------------------------- GEMM C = A @ BT^T
// A [M][K] bf16 row-major, BT [N][K] bf16 (n-major). 128x128 tile, BK=64, 4 waves.
// v2: T3-minimum 2-PHASE DOUBLE BUFFER — STAGE(k+1) issued BEFORE compute(k);
// one __syncthreads() per k-step (its vmcnt(0) drain is the "next buffer ready"
// guarantee — plain HIP, race-free by construction). Was: stage->barrier->
// compute->barrier single-buffer = zero overlap, 430 TF. Measured recipe value
// at K=1024: 622-682 TF (guide m228d/m230/m248).
// MODE 0: QKV epilogue -> scatter Q (prescaled), K, VT (transposed V), bf16.
// MODE 1: proj epilogue -> Out fp32 [M][N].
#define QSCALE 0.18033688011112042f   /* 0.125 * log2(e) */

template <int MODE>
__global__ __launch_bounds__(256)
void gemm_bt_kernel(const ushort* __restrict__ A, const ushort* __restrict__ BT,
                    const float* __restrict__ bias,
                    ushort* __restrict__ Qb, ushort* __restrict__ Kb,
                    ushort* __restrict__ VT, float* __restrict__ Out,
                    int M, int N, int K) {
    __shared__ ushort Asm[2][128 * 64];
    __shared__ ushort Bsm[2][128 * 64];
    const int lane = threadIdx.x & 63;
    const int wv = threadIdx.x >> 6;
    const int l15 = lane & 15, lg = lane >> 4;
    const int rm = (wv >> 1) * 64, cn = (wv & 1) * 64;  // wave's 64x64 sub-tile
    const int row0 = blockIdx.y * 128, col0 = blockIdx.x * 128;

    const char* Agb = (const char*)(A + (size_t)row0 * K);
    const char* Bgb = (const char*)(BT + (size_t)col0 * K);
    const size_t rowbytes = (size_t)K * 2;

    f32x4 acc[4][4];
#pragma unroll
    for (int mi = 0; mi < 4; ++mi)
#pragma unroll
        for (int ni = 0; ni < 4; ++ni) acc[mi][ni] = f32x4{0.f, 0.f, 0.f, 0.f};

    const int grow_l = (lane >> 3);          // 0..7 within 8-row chunk
    const int gcol_l = (lane & 7) * 16;      // byte within 128B row

#define GSTAGE(buf, k0_)                                                                \
    do {                                                                                \
        _Pragma("unroll")                                                               \
        for (int c_ = 0; c_ < 4; ++c_) {                                                \
            int chunk = wv * 4 + c_;                      /* 16 chunks of 1KB */        \
            size_t go = (size_t)(chunk * 8 + grow_l) * rowbytes + (size_t)(k0_)*2 +     \
                        gcol_l;                                                         \
            int lo = chunk * 1024 + lane * 16;                                          \
            __builtin_amdgcn_global_load_lds(                                           \
                (const __attribute__((address_space(1))) void*)(Agb + go),              \
                (__attribute__((address_space(3))) void*)((char*)&Asm[buf][0] + lo),    \
                16, 0, 0);                                                              \
            __builtin_amdgcn_global_load_lds(                                           \
                (const __attribute__((address_space(1))) void*)(Bgb + go),              \
                (__attribute__((address_space(3))) void*)((char*)&Bsm[buf][0] + lo),    \
                16, 0, 0);                                                              \
        }                                                                               \
    } while (0)

    GSTAGE(0, 0);
    __syncthreads();                                     // vmcnt(0) drain: buf0 ready

    int cur = 0;
    for (int k0 = 0; k0 < K; k0 += 64) {
        if (k0 + 64 < K) GSTAGE(cur ^ 1, k0 + 64);       // overlap with compute below
#pragma unroll
        for (int ks = 0; ks < 2; ++ks) {
            short8 af[4], bf[4];
#pragma unroll
            for (int mi = 0; mi < 4; ++mi)
                af[mi] = *(const short8*)&Asm[cur][(rm + mi * 16 + l15) * 64 + ks * 32 + lg * 8];
#pragma unroll
            for (int ni = 0; ni < 4; ++ni)
                bf[ni] = *(const short8*)&Bsm[cur][(cn + ni * 16 + l15) * 64 + ks * 32 + lg * 8];
#pragma unroll
            for (int mi = 0; mi < 4; ++mi)
#pragma unroll
                for (int ni = 0; ni < 4; ++ni)
                    acc[mi][ni] = MFMA16(af[mi], bf[ni], acc[mi][ni]);
        }
        __syncthreads();   // drains vmcnt(0): next buffer complete; cur safe to reuse
        cur ^= 1;
    }
#undef GSTAGE

    // Epilogue. D layout: lane holds D[(lg)*4+j][l15] (row=M dim, col=N dim).
    if (MODE == 0) {
        const int sect = col0 >> 10;   // 0=q 1=k 2=v, uniform per block (128 | 1024)
#pragma unroll
        for (int ni = 0; ni < 4; ++ni) {
            int col = col0 + cn + ni * 16 + l15;
            float bv = bias[col];
            int dcol = col & 1023, h = dcol >> 6, dd = dcol & 63;
#pragma unroll
            for (int mi = 0; mi < 4; ++mi) {
                int mrow0 = row0 + rm + mi * 16 + lg * 4;
                if (sect == 2) {
                    int b = mrow0 >> 11, s = mrow0 & 2047;   // 4 consecutive s, same b
                    u16x4 o;
#pragma unroll
                    for (int j = 0; j < 4; ++j) o[j] = f2bf(acc[mi][ni][j] + bv);
                    *(u16x4*)&VT[((size_t)((b << 4) + h) * 64 + dd) * 2048 + s] = o;
                } else {
                    ushort* dst = sect ? Kb : Qb;
                    float sc = sect ? 1.f : QSCALE;
#pragma unroll
                    for (int j = 0; j < 4; ++j) {
                        int tok = mrow0 + j;
                        int b = tok >> 11, s = tok & 2047;
                        dst[((size_t)((b << 4) + h) * 2048 + s) * 64 + dd] =
                            f2bf((acc[mi][ni][j] + bv) * sc);
                    }
                }
            }
        }
    } else {
#pragma unroll
        for (int ni = 0; ni < 4; ++ni) {
            int col = col0 + cn + ni * 16 + l15;
            float bv = bias[col];
#pragma unroll
            for (int mi = 0; mi < 4; ++mi) {
                int mrow0 = row0 + rm + mi * 16 + lg * 4;
#pragma unroll
                for (int j = 0; j < 4; ++j)
                    Out[(size_t)(mrow0 + j) * N + col] = acc[mi][ni][j] + bv;
            }
        }
    }
}

// ---------------------------------------------------------------- causal flash attention v8
// (unchanged from round 10 — 59.7us, verified)
__global__ __launch_bounds__(256)
void attn_kernel(const ushort* __restrict__ Qb, const ushort* __restrict__ Kb,
                 const ushort* __restrict__ VT, ushort* __restrict__ CTX) {
    __shared__ __align__(16) ushort Ksm[2][64 * 64];    // [key][d], 16B-slot XOR-swizzled
    __shared__ __align__(16) ushort Vsm[2][64 * 64];    // [d][key], 16B-slot XOR-swizzled

    const int tid = threadIdx.x;
    const int lane = tid & 63;
    const int w = tid >> 6;
    const int l31 = lane & 31;
    const int hi = lane >> 5;                            // 0/1
    const int r7 = l31 & 7;

    // block remap: 512 blocks = 8 xcd x (4 bh x 16 qt); complementary pairing.
    const int id = blockIdx.x;
    const int xcd = id & 7, jj = id >> 3;
    const int bh = (xcd << 2) + (jj >> 4);               // 4 heads per XCD -> K/V L2-resident
    const int qt = ((jj >> 5) & 1) ? (jj & 15) : 15 - (jj & 15);
    const int qw0 = qt * 128 + w * 32;                   // wave's 32 q-rows
    const int qrow = qw0 + l31;

    const ushort* Qh = Qb + (size_t)bh * 2048 * 64;
    const ushort* Kh = Kb + (size_t)bh * 2048 * 64;
    const ushort* Vh = VT + (size_t)bh * 64 * 2048;

    // Q fragments: B-operand of QK mfma: lane needs Q[qrow][dc*16+hi*8..+7]
    short8 qf[4];
#pragma unroll
    for (int dc = 0; dc < 4; ++dc)
        qf[dc] = *(const short8*)&Qh[(size_t)qrow * 64 + dc * 16 + hi * 8];

    // staging geometry: 256 threads, each owns rows {srow, srow+32} x one 16B col.
    const int srow = tid >> 3;                           // 0..31
    const int scol = tid & 7;                            // 16B col group
    const int swz8 = (scol ^ (srow & 7)) * 8;            // swizzled LDS col (elems)

    u32x4 kr0, kr1, vr0, vr1;                            // staged 16B each (T14)

#define LDREGS(kb_)                                                                     \
    do {                                                                                \
        const ushort* kp = Kh + (size_t)((kb_) + srow) * 64 + scol * 8;                 \
        kr0 = *(const u32x4*)kp;                                                        \
        kr1 = *(const u32x4*)(kp + 32 * 64);                                            \
        const ushort* vp = Vh + (size_t)srow * 2048 + (kb_) + scol * 8;                 \
        vr0 = *(const u32x4*)vp;                                                        \
        vr1 = *(const u32x4*)(vp + (size_t)32 * 2048);                                  \
    } while (0)

#define DSWRITE(buf)                                                                    \
    do {                                                                                \
        ushort* kd = &Ksm[buf][srow * 64 + swz8];                                       \
        *(u32x4*)kd = kr0;                                                              \
        *(u32x4*)(kd + 32 * 64) = kr1;                                                  \
        ushort* vd = &Vsm[buf][srow * 64 + swz8];                                       \
        *(u32x4*)vd = vr0;                                                              \
        *(u32x4*)(vd + 32 * 64) = vr1;                                                  \
    } while (0)

    const int nc = 2 * qt + 2;                           // 64-key chunks for this block
    const int cdiag = 2 * qt + (w >> 1);                 // wave's diagonal chunk

    LDREGS(0);
    DSWRITE(0);
    __syncthreads();

    float mrun = -1e30f, lsum = 0.f;
    f32x16 acc0, acc1;                                   // ctx^T d-tiles 0..31 / 32..63
#pragma unroll
    for (int r = 0; r < 16; ++r) { acc0[r] = 0.f; acc1[r] = 0.f; }

    int cur = 0;
    for (int c = 0; c < nc; ++c) {
        const int kb = c * 64;
        const bool havenext = (c + 1 < nc);
        if (havenext) LDREGS(kb + 64);                   // issue early: hide under compute

        if (!(w < 2 && c == nc - 1)) {                   // w0/1: last chunk fully masked
            const ushort* Kc = &Ksm[cur][0];
            const ushort* Vc = &Vsm[cur][0];

            // ---- K fragments: 8 ds_reads back-to-back (latencies overlap)
            short8 kf0[4], kf1[4];
#pragma unroll
            for (int dc = 0; dc < 4; ++dc) {
                kf0[dc] = *(const short8*)(Kc + l31 * 64 + (((dc * 2 + hi) ^ r7) << 3));
                kf1[dc] = *(const short8*)(Kc + (32 + l31) * 64 + (((dc * 2 + hi) ^ r7) << 3));
            }

            // ---- QK^T: two 32x32 S-tiles (keys kb..+31, kb+32..+63)
            f32x16 st0, st1;
#pragma unroll
            for (int r = 0; r < 16; ++r) { st0[r] = 0.f; st1[r] = 0.f; }
            __builtin_amdgcn_s_setprio(1);
#pragma unroll
            for (int dc = 0; dc < 4; ++dc) {
                st0 = MFMA32(kf0[dc], qf[dc], st0);
                st1 = MFMA32(kf1[dc], qf[dc], st1);
            }
            __builtin_amdgcn_s_setprio(0);

            // ---- causal mask (diagonal chunk only); key = base + (r&3) + 8*(r>>2)
            if (c == cdiag) {
                const int base0 = kb + (hi << 2);
                const int base1 = kb + 32 + (hi << 2);
#pragma unroll
                for (int r = 0; r < 16; ++r) {
                    int k0 = base0 + ((r & 3) + 8 * (r >> 2));
                    int k1 = base1 + ((r & 3) + 8 * (r >> 2));
                    st0[r] = (k0 <= qrow) ? st0[r] : -1e30f;
                    st1[r] = (k1 <= qrow) ? st1[r] : -1e30f;
                }
            }

            // ---- V fragments: 8 ds_reads issued now; latency hides under softmax.
            short8 vg0[4], vg1[4];
#pragma unroll
            for (int g = 0; g < 4; ++g) {
                vg0[g] = *(const short8*)(Vc + l31 * 64 + (((2 * g + hi) ^ r7) << 3));
                vg1[g] = *(const short8*)(Vc + (32 + l31) * 64 + (((2 * g + hi) ^ r7) << 3));
            }

            // ---- online softmax (log2 domain), defer-max THR=8
            float tmax = st0[0];
#pragma unroll
            for (int r = 1; r < 16; ++r) tmax = fmaxf(tmax, st0[r]);
#pragma unroll
            for (int r = 0; r < 16; ++r) tmax = fmaxf(tmax, st1[r]);
            tmax = fmaxf(tmax, __shfl_xor(tmax, 32));    // partner holds other half of row

            if (!__all(tmax <= mrun + 8.0f)) {
                float mnew = fmaxf(mrun, tmax);
                float sc = exp2f(mrun - mnew);
#pragma unroll
                for (int r = 0; r < 16; ++r) { acc0[r] *= sc; acc1[r] *= sc; }
                lsum *= sc;
                mrun = mnew;
            }

            float tsum = 0.f;
#pragma unroll
            for (int r = 0; r < 16; ++r) { st0[r] = exp2f(st0[r] - mrun); tsum += st0[r]; }
#pragma unroll
            for (int r = 0; r < 16; ++r) { st1[r] = exp2f(st1[r] - mrun); tsum += st1[r]; }
            lsum += tsum;                                // partner partial merged at end

            // ---- T14: commit staged regs to the other buffer mid-chunk
            if (havenext) DSWRITE(cur ^ 1);

            // ---- P re-frag in registers + PV (T12; verified round 4)
#define MAKE_PFRAG(st, kcL, out)                                                        \
    do {                                                                                \
        unsigned c00 = cvtpk(st[8 * kcL + 0], st[8 * kcL + 1]);                         \
        unsigned c01 = cvtpk(st[8 * kcL + 2], st[8 * kcL + 3]);                         \
        unsigned c10 = cvtpk(st[8 * kcL + 4], st[8 * kcL + 5]);                         \
        unsigned c11 = cvtpk(st[8 * kcL + 6], st[8 * kcL + 7]);                         \
        unsigned e0 = hi ? c00 : c10, e1 = hi ? c01 : c11;                              \
        unsigned pa0 = e0, pb0 = e0, pa1 = e1, pb1 = e1;                                \
        asm volatile("v_permlane32_swap_b32 %0, %1" : "+v"(pa0), "+v"(pb0));            \
        asm volatile("v_permlane32_swap_b32 %0, %1" : "+v"(pa1), "+v"(pb1));            \
        unsigned rec0 = hi ? pa0 : pb0;                                                 \
        unsigned rec1 = hi ? pa1 : pb1;                                                 \
        u32x4 fw;                                                                       \
        fw.x = hi ? rec0 : c00;                                                         \
        fw.y = hi ? rec1 : c01;                                                         \
        fw.z = hi ? c10 : rec0;                                                         \
        fw.w = hi ? c11 : rec1;                                                         \
        out = __builtin_bit_cast(short8, fw);                                           \
    } while (0)

            short8 pf;
            __builtin_amdgcn_s_setprio(1);
            MAKE_PFRAG(st0, 0, pf);
            acc0 = MFMA32(vg0[0], pf, acc0);
            acc1 = MFMA32(vg1[0], pf, acc1);
            MAKE_PFRAG(st0, 1, pf);
            acc0 = MFMA32(vg0[1], pf, acc0);
            acc1 = MFMA32(vg1[1], pf, acc1);
            MAKE_PFRAG(st1, 0, pf);
            acc0 = MFMA32(vg0[2], pf, acc0);
            acc1 = MFMA32(vg1[2], pf, acc1);
            MAKE_PFRAG(st1, 1, pf);
            acc0 = MFMA32(vg0[3], pf, acc0);
            acc1 = MFMA32(vg1[3], pf, acc1);
            __builtin_amdgcn_s_setprio(0);
#undef MAKE_PFRAG
        } else {
            if (havenext) DSWRITE(cur ^ 1);              // skip waves still stage
        }

        __syncthreads();
        cur ^= 1;
    }
#undef LDREGS
#undef DSWRITE

    lsum += __shfl_xor(lsum, 32);                        // merge partner halves
    const float inv = 1.f / lsum;
    const int b = bh >> 4, h = bh & 15;
    const size_t tokrow = ((size_t)b * 2048 + qw0 + l31) * 1024 + (size_t)h * 64;

#define WRITE_DT(accv, dt)                                                              \
    do {                                                                                \
        _Pragma("unroll")                                                               \
        for (int q2 = 0; q2 < 4; ++q2) {                                                \
            int d0 = dt * 32 + 8 * q2 + (hi << 2);                                      \
            u16x4 o;                                                                    \
            _Pragma("unroll")                                                           \
            for (int j = 0; j < 4; ++j) o[j] = f2bf(accv[4 * q2 + j] * inv);            \
            *(u16x4*)&CTX[tokrow + d0] = o;                                             \
        }                                                                               \
    } while (0)

    WRITE_DT(acc0, 0);
    WRITE_DT(acc1, 1);
#undef WRITE_DT
}

// ----------------------------------------------------------------------------
extern "C" void kernel_launch(void* const* d_in, const int* in_sizes, int n_in,
                              void* d_out, int out_size, void* d_ws, size_t ws_size,
                              hipStream_t stream) {
    const float* X     = (const float*)d_in[0];   // [2,2048,1024]
    const float* Wqkv  = (const float*)d_in[1];   // [1024,3072]
    const float* bqkv  = (const float*)d_in[2];   // [3072]
    const float* Wproj = (const float*)d_in[3];   // [1024,1024]
    const float* bproj = (const float*)d_in[4];   // [1024]
    float* Out = (float*)d_out;                   // [2,2048,1024] fp32

    // workspace layout (bf16 elements), total ~48 MB
    ushort* Xb     = (ushort*)d_ws;
    ushort* WqkvT  = Xb + (size_t)4096 * 1024;
    ushort* WprojT = WqkvT + (size_t)3072 * 1024;
    ushort* Qb     = WprojT + (size_t)1024 * 1024;  // [b,h,s,d] prescaled
    ushort* Kb     = Qb + (size_t)4096 * 1024;      // [b,h,s,d]
    ushort* VT     = Kb + (size_t)4096 * 1024;      // [b,h,d,s]
    ushort* CTX    = VT + (size_t)4096 * 1024;      // [tok, 1024] merged heads

    cast_x_kernel<<<4096, 256, 0, stream>>>(X, Xb);
    transpose_cast_kernel<<<dim3(48, 16), 256, 0, stream>>>(Wqkv, WqkvT, 1024, 3072);
    transpose_cast_kernel<<<dim3(16, 16), 256, 0, stream>>>(Wproj, WprojT, 1024, 1024);
    gemm_bt_kernel<0><<<dim3(24, 32), 256, 0, stream>>>(Xb, WqkvT, bqkv, Qb, Kb, VT, nullptr,
                                                        4096, 3072, 1024);
    attn_kernel<<<512, 256, 0, stream>>>(Qb, Kb, VT, CTX);
    gemm_bt_kernel<1><<<dim3(8, 32), 256, 0, stream>>>(CTX, WprojT, bproj, nullptr, nullptr,
                                                       nullptr, Out, 4096, 1024, 1024);
}

// Round 12
// 130.299 us; speedup vs baseline: 1.1465x; 1.1465x over previous
//
#include <hip/hip_runtime.h>
#include <hip/hip_bf16.h>

typedef __attribute__((ext_vector_type(8))) short short8;     // 8 bf16 (4 VGPRs) MFMA A/B frag
typedef __attribute__((ext_vector_type(4))) float f32x4;      // 16x16 MFMA C/D frag
typedef __attribute__((ext_vector_type(16))) float f32x16;    // 32x32 MFMA C/D frag
typedef __attribute__((ext_vector_type(4))) unsigned short u16x4;
typedef __attribute__((ext_vector_type(4))) unsigned int u32x4;

#define MFMA16(a, b, c) __builtin_amdgcn_mfma_f32_16x16x32_bf16((a), (b), (c), 0, 0, 0)
#define MFMA32(a, b, c) __builtin_amdgcn_mfma_f32_32x32x16_bf16((a), (b), (c), 0, 0, 0)

__device__ __forceinline__ unsigned short f2bf(float f) {
    union { float f; unsigned u; } v; v.f = f;
    return (unsigned short)((v.u + 0x7fffu + ((v.u >> 16) & 1u)) >> 16);
}

__device__ __forceinline__ unsigned cvtpk(float lo, float hi_) {
    unsigned r;
    asm volatile("v_cvt_pk_bf16_f32 %0, %1, %2" : "=v"(r) : "v"(lo), "v"(hi_));
    return r;
}

// ---------------------------------------------------------------- cast X -> bf16
__global__ void cast_x_kernel(const float* __restrict__ x, ushort* __restrict__ y) {
    int i = blockIdx.x * blockDim.x + threadIdx.x;      // one float4 per thread, exact grid
    float4 v = ((const float4*)x)[i];
    u16x4 o = { f2bf(v.x), f2bf(v.y), f2bf(v.z), f2bf(v.w) };
    *(u16x4*)(y + (size_t)i * 4) = o;
}

// ------------------------------------------- W [K][N] f32 -> WT [N][K] bf16
__global__ void transpose_cast_kernel(const float* __restrict__ W, ushort* __restrict__ WT,
                                      int K, int N) {
    __shared__ ushort t[64][66];                        // 66: odd word stride, conflict-free
    int n0 = blockIdx.x * 64, k0 = blockIdx.y * 64;
    int tn = threadIdx.x & 63, tg = threadIdx.x >> 6;
#pragma unroll
    for (int i = 0; i < 16; ++i) {
        int k = tg * 16 + i;
        t[tn][k] = f2bf(W[(size_t)(k0 + k) * N + n0 + tn]);
    }
    __syncthreads();
#pragma unroll
    for (int i = 0; i < 16; ++i) {
        int nn = tg * 16 + i;
        WT[(size_t)(n0 + nn) * K + k0 + tn] = t[nn][tn];
    }
}

// ---------------------------------------------------------------- GEMM C = A @ BT^T
// A [M][K] bf16 row-major, BT [N][K] bf16 (n-major). 128x128 tile, 4 waves.
// v3: BK=32 double-buffer (LDS 32KB -> 3 blocks/CU, grid 768 FULLY co-resident,
// zero tail) + XOR slot-swizzle (rule #21): gload_lds SOURCE col = slot^(row&3),
// ds_read col factor = lg^(l15&3) -> 16-way bank conflict cut to 4-way.
// Round-11 PMC showed LDS-read (1536+conflict cyc/CU/step) > MFMA (1242) was the
// binding pipe, and 64KB LDS caused a 1.5-round tail.
// MODE 0: QKV epilogue -> scatter Q (prescaled), K, VT (transposed V), bf16.
// MODE 1: proj epilogue -> Out fp32 [M][N].
#define QSCALE 0.18033688011112042f   /* 0.125 * log2(e) */

template <int MODE>
__global__ __launch_bounds__(256, 3)
void gemm_bt_kernel(const ushort* __restrict__ A, const ushort* __restrict__ BT,
                    const float* __restrict__ bias,
                    ushort* __restrict__ Qb, ushort* __restrict__ Kb,
                    ushort* __restrict__ VT, float* __restrict__ Out,
                    int M, int N, int K) {
    __shared__ ushort Asm[2][128 * 32];                 // [row][32], 16B-slot swizzled
    __shared__ ushort Bsm[2][128 * 32];
    const int tid = threadIdx.x;
    const int lane = tid & 63;
    const int wv = tid >> 6;
    const int l15 = lane & 15, lg = lane >> 4;
    const int rm = (wv >> 1) * 64, cn = (wv & 1) * 64;  // wave's 64x64 sub-tile
    const int row0 = blockIdx.y * 128, col0 = blockIdx.x * 128;

    const char* Agb = (const char*)(A + (size_t)row0 * K);
    const char* Bgb = (const char*)(BT + (size_t)col0 * K);
    const size_t rowbytes = (size_t)K * 2;

    f32x4 acc[4][4];
#pragma unroll
    for (int mi = 0; mi < 4; ++mi)
#pragma unroll
        for (int ni = 0; ni < 4; ++ni) acc[mi][ni] = f32x4{0.f, 0.f, 0.f, 0.f};

    // staging: 512 slots (128 rows x 4 x16B), 2 per thread; source col swizzled.
    const int sr0 = tid >> 2, sc0 = (tid & 3) ^ (sr0 & 3);          // slot tid
    const int sr1 = (tid + 256) >> 2, sc1 = (tid & 3) ^ (sr1 & 3);  // slot tid+256

#define GSTAGE(buf, k0_)                                                                \
    do {                                                                                \
        size_t kbyte = (size_t)(k0_)*2;                                                 \
        __builtin_amdgcn_global_load_lds(                                               \
            (const __attribute__((address_space(1))) void*)(Agb + (size_t)sr0 *         \
                rowbytes + kbyte + sc0 * 16),                                           \
            (__attribute__((address_space(3))) void*)((char*)&Asm[buf][0] + tid * 16),  \
            16, 0, 0);                                                                  \
        __builtin_amdgcn_global_load_lds(                                               \
            (const __attribute__((address_space(1))) void*)(Agb + (size_t)sr1 *         \
                rowbytes + kbyte + sc1 * 16),                                           \
            (__attribute__((address_space(3))) void*)((char*)&Asm[buf][0] + 4096 +      \
                tid * 16),                                                              \
            16, 0, 0);                                                                  \
        __builtin_amdgcn_global_load_lds(                                               \
            (const __attribute__((address_space(1))) void*)(Bgb + (size_t)sr0 *         \
                rowbytes + kbyte + sc0 * 16),                                           \
            (__attribute__((address_space(3))) void*)((char*)&Bsm[buf][0] + tid * 16),  \
            16, 0, 0);                                                                  \
        __builtin_amdgcn_global_load_lds(                                               \
            (const __attribute__((address_space(1))) void*)(Bgb + (size_t)sr1 *         \
                rowbytes + kbyte + sc1 * 16),                                           \
            (__attribute__((address_space(3))) void*)((char*)&Bsm[buf][0] + 4096 +      \
                tid * 16),                                                              \
            16, 0, 0);                                                                  \
    } while (0)

    GSTAGE(0, 0);
    __syncthreads();                                     // vmcnt(0) drain: buf0 ready

    // read swizzle: row R, elems lg*8..+7 live at slot lg^(R&3); R&3 == l15&3.
    const int sw8 = (lg ^ (l15 & 3)) << 3;

    int cur = 0;
    for (int k0 = 0; k0 < K; k0 += 32) {
        if (k0 + 32 < K) GSTAGE(cur ^ 1, k0 + 32);       // overlap with compute below
        short8 af[4], bf[4];
#pragma unroll
        for (int mi = 0; mi < 4; ++mi)
            af[mi] = *(const short8*)&Asm[cur][(rm + mi * 16 + l15) * 32 + sw8];
#pragma unroll
        for (int ni = 0; ni < 4; ++ni)
            bf[ni] = *(const short8*)&Bsm[cur][(cn + ni * 16 + l15) * 32 + sw8];
        __builtin_amdgcn_s_setprio(1);
#pragma unroll
        for (int mi = 0; mi < 4; ++mi)
#pragma unroll
            for (int ni = 0; ni < 4; ++ni)
                acc[mi][ni] = MFMA16(af[mi], bf[ni], acc[mi][ni]);
        __builtin_amdgcn_s_setprio(0);
        __syncthreads();   // drains vmcnt(0): next buffer complete; cur safe to reuse
        cur ^= 1;
    }
#undef GSTAGE

    // Epilogue. D layout: lane holds D[(lg)*4+j][l15] (row=M dim, col=N dim).
    if (MODE == 0) {
        const int sect = col0 >> 10;   // 0=q 1=k 2=v, uniform per block (128 | 1024)
#pragma unroll
        for (int ni = 0; ni < 4; ++ni) {
            int col = col0 + cn + ni * 16 + l15;
            float bv = bias[col];
            int dcol = col & 1023, h = dcol >> 6, dd = dcol & 63;
#pragma unroll
            for (int mi = 0; mi < 4; ++mi) {
                int mrow0 = row0 + rm + mi * 16 + lg * 4;
                if (sect == 2) {
                    int b = mrow0 >> 11, s = mrow0 & 2047;   // 4 consecutive s, same b
                    u16x4 o;
#pragma unroll
                    for (int j = 0; j < 4; ++j) o[j] = f2bf(acc[mi][ni][j] + bv);
                    *(u16x4*)&VT[((size_t)((b << 4) + h) * 64 + dd) * 2048 + s] = o;
                } else {
                    ushort* dst = sect ? Kb : Qb;
                    float sc = sect ? 1.f : QSCALE;
#pragma unroll
                    for (int j = 0; j < 4; ++j) {
                        int tok = mrow0 + j;
                        int b = tok >> 11, s = tok & 2047;
                        dst[((size_t)((b << 4) + h) * 2048 + s) * 64 + dd] =
                            f2bf((acc[mi][ni][j] + bv) * sc);
                    }
                }
            }
        }
    } else {
#pragma unroll
        for (int ni = 0; ni < 4; ++ni) {
            int col = col0 + cn + ni * 16 + l15;
            float bv = bias[col];
#pragma unroll
            for (int mi = 0; mi < 4; ++mi) {
                int mrow0 = row0 + rm + mi * 16 + lg * 4;
#pragma unroll
                for (int j = 0; j < 4; ++j)
                    Out[(size_t)(mrow0 + j) * N + col] = acc[mi][ni][j] + bv;
            }
        }
    }
}

// ---------------------------------------------------------------- causal flash attention v8
// (unchanged from round 10 — 59.7us, verified)
__global__ __launch_bounds__(256)
void attn_kernel(const ushort* __restrict__ Qb, const ushort* __restrict__ Kb,
                 const ushort* __restrict__ VT, ushort* __restrict__ CTX) {
    __shared__ __align__(16) ushort Ksm[2][64 * 64];    // [key][d], 16B-slot XOR-swizzled
    __shared__ __align__(16) ushort Vsm[2][64 * 64];    // [d][key], 16B-slot XOR-swizzled

    const int tid = threadIdx.x;
    const int lane = tid & 63;
    const int w = tid >> 6;
    const int l31 = lane & 31;
    const int hi = lane >> 5;                            // 0/1
    const int r7 = l31 & 7;

    // block remap: 512 blocks = 8 xcd x (4 bh x 16 qt); complementary pairing.
    const int id = blockIdx.x;
    const int xcd = id & 7, jj = id >> 3;
    const int bh = (xcd << 2) + (jj >> 4);               // 4 heads per XCD -> K/V L2-resident
    const int qt = ((jj >> 5) & 1) ? (jj & 15) : 15 - (jj & 15);
    const int qw0 = qt * 128 + w * 32;                   // wave's 32 q-rows
    const int qrow = qw0 + l31;

    const ushort* Qh = Qb + (size_t)bh * 2048 * 64;
    const ushort* Kh = Kb + (size_t)bh * 2048 * 64;
    const ushort* Vh = VT + (size_t)bh * 64 * 2048;

    // Q fragments: B-operand of QK mfma: lane needs Q[qrow][dc*16+hi*8..+7]
    short8 qf[4];
#pragma unroll
    for (int dc = 0; dc < 4; ++dc)
        qf[dc] = *(const short8*)&Qh[(size_t)qrow * 64 + dc * 16 + hi * 8];

    // staging geometry: 256 threads, each owns rows {srow, srow+32} x one 16B col.
    const int srow = tid >> 3;                           // 0..31
    const int scol = tid & 7;                            // 16B col group
    const int swz8 = (scol ^ (srow & 7)) * 8;            // swizzled LDS col (elems)

    u32x4 kr0, kr1, vr0, vr1;                            // staged 16B each (T14)

#define LDREGS(kb_)                                                                     \
    do {                                                                                \
        const ushort* kp = Kh + (size_t)((kb_) + srow) * 64 + scol * 8;                 \
        kr0 = *(const u32x4*)kp;                                                        \
        kr1 = *(const u32x4*)(kp + 32 * 64);                                            \
        const ushort* vp = Vh + (size_t)srow * 2048 + (kb_) + scol * 8;                 \
        vr0 = *(const u32x4*)vp;                                                        \
        vr1 = *(const u32x4*)(vp + (size_t)32 * 2048);                                  \
    } while (0)

#define DSWRITE(buf)                                                                    \
    do {                                                                                \
        ushort* kd = &Ksm[buf][srow * 64 + swz8];                                       \
        *(u32x4*)kd = kr0;                                                              \
        *(u32x4*)(kd + 32 * 64) = kr1;                                                  \
        ushort* vd = &Vsm[buf][srow * 64 + swz8];                                       \
        *(u32x4*)vd = vr0;                                                              \
        *(u32x4*)(vd + 32 * 64) = vr1;                                                  \
    } while (0)

    const int nc = 2 * qt + 2;                           // 64-key chunks for this block
    const int cdiag = 2 * qt + (w >> 1);                 // wave's diagonal chunk

    LDREGS(0);
    DSWRITE(0);
    __syncthreads();

    float mrun = -1e30f, lsum = 0.f;
    f32x16 acc0, acc1;                                   // ctx^T d-tiles 0..31 / 32..63
#pragma unroll
    for (int r = 0; r < 16; ++r) { acc0[r] = 0.f; acc1[r] = 0.f; }

    int cur = 0;
    for (int c = 0; c < nc; ++c) {
        const int kb = c * 64;
        const bool havenext = (c + 1 < nc);
        if (havenext) LDREGS(kb + 64);                   // issue early: hide under compute

        if (!(w < 2 && c == nc - 1)) {                   // w0/1: last chunk fully masked
            const ushort* Kc = &Ksm[cur][0];
            const ushort* Vc = &Vsm[cur][0];

            // ---- K fragments: 8 ds_reads back-to-back (latencies overlap)
            short8 kf0[4], kf1[4];
#pragma unroll
            for (int dc = 0; dc < 4; ++dc) {
                kf0[dc] = *(const short8*)(Kc + l31 * 64 + (((dc * 2 + hi) ^ r7) << 3));
                kf1[dc] = *(const short8*)(Kc + (32 + l31) * 64 + (((dc * 2 + hi) ^ r7) << 3));
            }

            // ---- QK^T: two 32x32 S-tiles (keys kb..+31, kb+32..+63)
            f32x16 st0, st1;
#pragma unroll
            for (int r = 0; r < 16; ++r) { st0[r] = 0.f; st1[r] = 0.f; }
            __builtin_amdgcn_s_setprio(1);
#pragma unroll
            for (int dc = 0; dc < 4; ++dc) {
                st0 = MFMA32(kf0[dc], qf[dc], st0);
                st1 = MFMA32(kf1[dc], qf[dc], st1);
            }
            __builtin_amdgcn_s_setprio(0);

            // ---- causal mask (diagonal chunk only); key = base + (r&3) + 8*(r>>2)
            if (c == cdiag) {
                const int base0 = kb + (hi << 2);
                const int base1 = kb + 32 + (hi << 2);
#pragma unroll
                for (int r = 0; r < 16; ++r) {
                    int k0 = base0 + ((r & 3) + 8 * (r >> 2));
                    int k1 = base1 + ((r & 3) + 8 * (r >> 2));
                    st0[r] = (k0 <= qrow) ? st0[r] : -1e30f;
                    st1[r] = (k1 <= qrow) ? st1[r] : -1e30f;
                }
            }

            // ---- V fragments: 8 ds_reads issued now; latency hides under softmax.
            short8 vg0[4], vg1[4];
#pragma unroll
            for (int g = 0; g < 4; ++g) {
                vg0[g] = *(const short8*)(Vc + l31 * 64 + (((2 * g + hi) ^ r7) << 3));
                vg1[g] = *(const short8*)(Vc + (32 + l31) * 64 + (((2 * g + hi) ^ r7) << 3));
            }

            // ---- online softmax (log2 domain), defer-max THR=8
            float tmax = st0[0];
#pragma unroll
            for (int r = 1; r < 16; ++r) tmax = fmaxf(tmax, st0[r]);
#pragma unroll
            for (int r = 0; r < 16; ++r) tmax = fmaxf(tmax, st1[r]);
            tmax = fmaxf(tmax, __shfl_xor(tmax, 32));    // partner holds other half of row

            if (!__all(tmax <= mrun + 8.0f)) {
                float mnew = fmaxf(mrun, tmax);
                float sc = exp2f(mrun - mnew);
#pragma unroll
                for (int r = 0; r < 16; ++r) { acc0[r] *= sc; acc1[r] *= sc; }
                lsum *= sc;
                mrun = mnew;
            }

            float tsum = 0.f;
#pragma unroll
            for (int r = 0; r < 16; ++r) { st0[r] = exp2f(st0[r] - mrun); tsum += st0[r]; }
#pragma unroll
            for (int r = 0; r < 16; ++r) { st1[r] = exp2f(st1[r] - mrun); tsum += st1[r]; }
            lsum += tsum;                                // partner partial merged at end

            // ---- T14: commit staged regs to the other buffer mid-chunk
            if (havenext) DSWRITE(cur ^ 1);

            // ---- P re-frag in registers + PV (T12; verified round 4)
#define MAKE_PFRAG(st, kcL, out)                                                        \
    do {                                                                                \
        unsigned c00 = cvtpk(st[8 * kcL + 0], st[8 * kcL + 1]);                         \
        unsigned c01 = cvtpk(st[8 * kcL + 2], st[8 * kcL + 3]);                         \
        unsigned c10 = cvtpk(st[8 * kcL + 4], st[8 * kcL + 5]);                         \
        unsigned c11 = cvtpk(st[8 * kcL + 6], st[8 * kcL + 7]);                         \
        unsigned e0 = hi ? c00 : c10, e1 = hi ? c01 : c11;                              \
        unsigned pa0 = e0, pb0 = e0, pa1 = e1, pb1 = e1;                                \
        asm volatile("v_permlane32_swap_b32 %0, %1" : "+v"(pa0), "+v"(pb0));            \
        asm volatile("v_permlane32_swap_b32 %0, %1" : "+v"(pa1), "+v"(pb1));            \
        unsigned rec0 = hi ? pa0 : pb0;                                                 \
        unsigned rec1 = hi ? pa1 : pb1;                                                 \
        u32x4 fw;                                                                       \
        fw.x = hi ? rec0 : c00;                                                         \
        fw.y = hi ? rec1 : c01;                                                         \
        fw.z = hi ? c10 : rec0;                                                         \
        fw.w = hi ? c11 : rec1;                                                         \
        out = __builtin_bit_cast(short8, fw);                                           \
    } while (0)

            short8 pf;
            __builtin_amdgcn_s_setprio(1);
            MAKE_PFRAG(st0, 0, pf);
            acc0 = MFMA32(vg0[0], pf, acc0);
            acc1 = MFMA32(vg1[0], pf, acc1);
            MAKE_PFRAG(st0, 1, pf);
            acc0 = MFMA32(vg0[1], pf, acc0);
            acc1 = MFMA32(vg1[1], pf, acc1);
            MAKE_PFRAG(st1, 0, pf);
            acc0 = MFMA32(vg0[2], pf, acc0);
            acc1 = MFMA32(vg1[2], pf, acc1);
            MAKE_PFRAG(st1, 1, pf);
            acc0 = MFMA32(vg0[3], pf, acc0);
            acc1 = MFMA32(vg1[3], pf, acc1);
            __builtin_amdgcn_s_setprio(0);
#undef MAKE_PFRAG
        } else {
            if (havenext) DSWRITE(cur ^ 1);              // skip waves still stage
        }

        __syncthreads();
        cur ^= 1;
    }
#undef LDREGS
#undef DSWRITE

    lsum += __shfl_xor(lsum, 32);                        // merge partner halves
    const float inv = 1.f / lsum;
    const int b = bh >> 4, h = bh & 15;
    const size_t tokrow = ((size_t)b * 2048 + qw0 + l31) * 1024 + (size_t)h * 64;

#define WRITE_DT(accv, dt)                                                              \
    do {                                                                                \
        _Pragma("unroll")                                                               \
        for (int q2 = 0; q2 < 4; ++q2) {                                                \
            int d0 = dt * 32 + 8 * q2 + (hi << 2);                                      \
            u16x4 o;                                                                    \
            _Pragma("unroll")                                                           \
            for (int j = 0; j < 4; ++j) o[j] = f2bf(accv[4 * q2 + j] * inv);            \
            *(u16x4*)&CTX[tokrow + d0] = o;                                             \
        }                                                                               \
    } while (0)

    WRITE_DT(acc0, 0);
    WRITE_DT(acc1, 1);
#undef WRITE_DT
}

// ----------------------------------------------------------------------------
extern "C" void kernel_launch(void* const* d_in, const int* in_sizes, int n_in,
                              void* d_out, int out_size, void* d_ws, size_t ws_size,
                              hipStream_t stream) {
    const float* X     = (const float*)d_in[0];   // [2,2048,1024]
    const float* Wqkv  = (const float*)d_in[1];   // [1024,3072]
    const float* bqkv  = (const float*)d_in[2];   // [3072]
    const float* Wproj = (const float*)d_in[3];   // [1024,1024]
    const float* bproj = (const float*)d_in[4];   // [1024]
    float* Out = (float*)d_out;                   // [2,2048,1024] fp32

    // workspace layout (bf16 elements), total ~48 MB
    ushort* Xb     = (ushort*)d_ws;
    ushort* WqkvT  = Xb + (size_t)4096 * 1024;
    ushort* WprojT = WqkvT + (size_t)3072 * 1024;
    ushort* Qb     = WprojT + (size_t)1024 * 1024;  // [b,h,s,d] prescaled
    ushort* Kb     = Qb + (size_t)4096 * 1024;      // [b,h,s,d]
    ushort* VT     = Kb + (size_t)4096 * 1024;      // [b,h,d,s]
    ushort* CTX    = VT + (size_t)4096 * 1024;      // [tok, 1024] merged heads

    cast_x_kernel<<<4096, 256, 0, stream>>>(X, Xb);
    transpose_cast_kernel<<<dim3(48, 16), 256, 0, stream>>>(Wqkv, WqkvT, 1024, 3072);
    transpose_cast_kernel<<<dim3(16, 16), 256, 0, stream>>>(Wproj, WprojT, 1024, 1024);
    gemm_bt_kernel<0><<<dim3(24, 32), 256, 0, stream>>>(Xb, WqkvT, bqkv, Qb, Kb, VT, nullptr,
                                                        4096, 3072, 1024);
    attn_kernel<<<512, 256, 0, stream>>>(Qb, Kb, VT, CTX);
    gemm_bt_kernel<1><<<dim3(8, 32), 256, 0, stream>>>(CTX, WprojT, bproj, nullptr, nullptr,
                                                       nullptr, Out, 4096, 1024, 1024);
}